// Round 12
// baseline (251.222 us; speedup 1.0000x reference)
//
#include <hip/hip_runtime.h>

#define NS 32768
#define NE 4

typedef __attribute__((ext_vector_type(4))) float f32x4;
typedef __attribute__((ext_vector_type(8))) short bf16x8;

// fp32 -> bf16, round-to-nearest-even
__device__ __forceinline__ unsigned short f2bf(float f) {
    unsigned int u = __float_as_uint(f);
    u = (u + 0x7fffu + ((u >> 16) & 1u)) >> 16;
    return (unsigned short)u;
}

__device__ __forceinline__ int expert_of(const float4 yr) {
    int e = 0;
    if (yr.y > 0.5f) e = 1;
    else if (yr.z > 0.5f) e = 2;
    else if (yr.w > 0.5f) e = 3;
    return e;
}

// Prep A: blocks 0..15 transpose W -> Wt bf16; blocks 16..143 count experts
// per 256-sample chunk into bcnt[e][chunk] (block-exclusive, no atomics).
__global__ void prep_count(const float* __restrict__ W,
                           unsigned short* __restrict__ Wt,
                           const float* __restrict__ y,
                           int* __restrict__ bcnt) {
    const int b = blockIdx.x;
    if (b < 16) {
        const float* w = W + (size_t)b * 16384;         // [c][k]
        unsigned short* wt = Wt + (size_t)b * 16384;    // [k][c]
        for (int i = threadIdx.x; i < 16384; i += 256) {
            int c = i & 127, k = i >> 7;
            wt[k * 128 + c] = f2bf(w[c * 128 + k]);
        }
        return;
    }
    __shared__ int c[4][4];                             // [wave][expert]
    const int blk = b - 16;                             // 0..127
    int n = blk * 256 + threadIdx.x;
    int e = expert_of(((const float4*)y)[n]);
    const int lane = threadIdx.x & 63;
    const int wv = threadIdx.x >> 6;
#pragma unroll
    for (int ee = 0; ee < NE; ++ee) {
        unsigned long long m = __ballot(e == ee);
        if (lane == 0) c[wv][ee] = __popcll(m);
    }
    __syncthreads();
    if (threadIdx.x < 4)
        bcnt[threadIdx.x * 128 + blk] = c[0][threadIdx.x] + c[1][threadIdx.x] +
                                        c[2][threadIdx.x] + c[3][threadIdx.x];
}

// Prep B (merged scan+fill): each block computes its own expert offsets by
// wave-reducing bcnt directly, then writes idx sorted by n per expert.
__global__ void prep_fill(const float* __restrict__ y,
                          const int* __restrict__ bcnt, int* __restrict__ idx,
                          int* __restrict__ cnt) {
    __shared__ int sh_boff[4];
    __shared__ int wcnt[4][4];                // [wave][expert]
    const int blk = blockIdx.x;               // 0..127
    const int lane = threadIdx.x & 63;
    const int wv = threadIdx.x >> 6;          // 0..3 == expert for the scan
    {
        int c0 = bcnt[wv * 128 + lane];
        int c1 = bcnt[wv * 128 + 64 + lane];
        int part = ((lane < blk) ? c0 : 0) + ((lane + 64 < blk) ? c1 : 0);
        int tot = c0 + c1;
#pragma unroll
        for (int d = 1; d < 64; d <<= 1) {
            part += __shfl_xor(part, d);
            tot += __shfl_xor(tot, d);
        }
        if (lane == 0) {
            sh_boff[wv] = part;
            if (blk == 0) cnt[wv] = tot;
        }
    }
    int n = blk * 256 + threadIdx.x;
    int e = expert_of(((const float4*)y)[n]);
    int rank = 0;
#pragma unroll
    for (int ee = 0; ee < NE; ++ee) {
        unsigned long long m = __ballot(e == ee);
        if (lane == 0) wcnt[wv][ee] = __popcll(m);
        if (e == ee) rank = __popcll(m & ((1ull << lane) - 1ull));
    }
    __syncthreads();
#pragma unroll
    for (int w = 0; w < 4; ++w)
        if (w < wv) rank += wcnt[w][e];
    idx[e * NS + sh_boff[e] + rank] = n;
}

// One pure-l 16-row subtile inside a 16-sample window. Window sample q
// (q in [0,16)) contributes M rows; row index within the window's l-rows is
// r = q*M + j. Subtile s_l covers r in [16*s_l, 16*s_l+16).
// wpan = LDS weight panel base (XOR-swizzled); xl = wave-private x tile.
template <int L, int M>
__device__ __forceinline__ void sub_tile(
    int s_l, int tile, int cnt_e, const int* __restrict__ idxe,
    const float* __restrict__ x, const unsigned char* __restrict__ wpan,
    unsigned char* __restrict__ xl, float* __restrict__ out) {
    const int lane = threadIdx.x & 63;
    const int li = lane & 15;
    const int half = lane >> 4;   // 0..3
    const int i5 = lane >> 5;     // 0..1
    const int c32 = lane & 31;

    // Stage 16 rows: instr p covers rows 2p,2p+1 (contiguous within samples).
    f32x4 bv[8];
#pragma unroll
    for (int p = 0; p < 8; ++p) {
        int r = s_l * 16 + 2 * p + i5;
        int q = r / M;                        // compile-time M -> magic mul
        int j = r - q * M;
        int pos = tile * 16 + q;
        int pc = pos < cnt_e ? pos : cnt_e - 1;   // clamp for safe loads
        int row = idxe[pc] * 16 + L * L + j;
        bv[p] = *(const f32x4*)(x + (size_t)row * 128 + c32 * 4);
    }
#pragma unroll
    for (int p = 0; p < 8; ++p) {
        int tr = 2 * p + i5;
        unsigned int p0 = (unsigned int)f2bf(bv[p].x) |
                          ((unsigned int)f2bf(bv[p].y) << 16);
        unsigned int p1 = (unsigned int)f2bf(bv[p].z) |
                          ((unsigned int)f2bf(bv[p].w) << 16);
        uint2 pk; pk.x = p0; pk.y = p1;
        int off = (c32 * 8) ^ ((tr & 7) << 4);
        *(uint2*)(xl + tr * 256 + off) = pk;
    }

    f32x4 acc[8];
#pragma unroll
    for (int t = 0; t < 8; ++t) acc[t] = (f32x4){0.f, 0.f, 0.f, 0.f};

#pragma unroll
    for (int kk = 0; kk < 4; ++kk) {
        int co = (kk * 64 + half * 16) ^ ((li & 7) << 4);
        bf16x8 bfrag = *(const bf16x8*)(xl + li * 256 + co);
#pragma unroll
        for (int t = 0; t < 8; ++t) {
            bf16x8 afrag = *(const bf16x8*)(wpan + (t * 16 + li) * 256 + co);
            acc[t] = __builtin_amdgcn_mfma_f32_16x16x32_bf16(afrag, bfrag,
                                                             acc[t], 0, 0, 0);
        }
    }

    {
        int r = s_l * 16 + li;
        int q = r / M;
        int j = r - q * M;
        int pos = tile * 16 + q;
        if (pos < cnt_e) {
            float* orow = out + (size_t)(idxe[pos] * 16 + L * L + j) * 128;
            const float pw = 0.088388347648318447f;  // 1/sqrt(128)
#pragma unroll
            for (int t = 0; t < 8; ++t) {
                *(f32x4*)(orow + t * 16 + half * 4) = acc[t] * pw;
            }
        }
    }
}

// Sample-slab-unified GEMM. A 16-sample window = 256 rows = 16 pure-l
// subtiles (1+3+5+7), split across two pair-blocks that are ADJACENT in
// dispatch order: pair 0 = (l0,l3) (1+7=8 subtiles), pair 1 = (l1,l2)
// (3+5=8 subtiles). Both read/write the same sample slabs in the same time
// window -> each 8 KB slab is one DRAM visit (L3 merges the halves).
// LDS: [0,32K) panel A, [32K,64K) panel B (both XOR-swizzled),
//      [64K,80K) 4 wave-private x tiles. 80 KB -> 2 blocks/CU.
__global__ __launch_bounds__(256, 2) void gemm_main(
    const float* __restrict__ x, const unsigned short* __restrict__ Wt,
    const int* __restrict__ cnt, const int* __restrict__ idx,
    float* __restrict__ out) {
    __shared__ __align__(16) unsigned char lds[81920];
    const int b = blockIdx.x;
    const int e = b >> 10;
    const int rem = b & 1023;
    const int pair = rem & 1;
    const int u = rem >> 1;                   // 4-tile super-tile index
    const int cnt_e = cnt[e];
    if (u * 64 >= cnt_e) return;

    // Stage the two panels (contiguous 4 KB per instruction, 16 total).
    {
        const unsigned char* pa =
            (const unsigned char*)(Wt + (size_t)(e * 4 + (pair ? 1 : 0)) * 16384);
        const unsigned char* pb =
            (const unsigned char*)(Wt + (size_t)(e * 4 + (pair ? 2 : 3)) * 16384);
        const int t = threadIdx.x;
#pragma unroll
        for (int qq = 0; qq < 8; ++qq) {
            int o = qq * 4096 + t * 16;
            uint4 va = *(const uint4*)(pa + o);
            uint4 vb = *(const uint4*)(pb + o);
            int so = o ^ (((o >> 8) & 7) << 4);   // o>>8 = k row (256 B rows)
            *(uint4*)(lds + so) = va;
            *(uint4*)(lds + 32768 + so) = vb;
        }
    }
    __syncthreads();

    const int wv = threadIdx.x >> 6;          // 0..3
    const int* idxe = idx + e * NS;
    unsigned char* xl = lds + 65536 + wv * 4096;  // wave-private x tile

    for (int tt = 0; tt < 4; ++tt) {
        int tile = u * 4 + tt;
        if (tile * 16 >= cnt_e) break;
        if (pair == 0) {
            // subtiles: s=0 -> (l0,0); s in [1,8) -> (l3, s-1); wave w does
            // s=w and s=w+4.
            if (wv == 0) {
                sub_tile<0, 1>(0, tile, cnt_e, idxe, x, lds, xl, out);
                sub_tile<3, 7>(3, tile, cnt_e, idxe, x, lds + 32768, xl, out);
            } else {
                sub_tile<3, 7>(wv - 1, tile, cnt_e, idxe, x, lds + 32768, xl, out);
                sub_tile<3, 7>(wv + 3, tile, cnt_e, idxe, x, lds + 32768, xl, out);
            }
        } else {
            // subtiles: s in [0,3) -> (l1, s); s in [3,8) -> (l2, s-3).
            if (wv < 3) {
                sub_tile<1, 3>(wv, tile, cnt_e, idxe, x, lds, xl, out);
                sub_tile<2, 5>(wv + 1, tile, cnt_e, idxe, x, lds + 32768, xl, out);
            } else {
                sub_tile<2, 5>(0, tile, cnt_e, idxe, x, lds + 32768, xl, out);
                sub_tile<2, 5>(4, tile, cnt_e, idxe, x, lds + 32768, xl, out);
            }
        }
    }
}

extern "C" void kernel_launch(void* const* d_in, const int* in_sizes, int n_in,
                              void* d_out, int out_size, void* d_ws,
                              size_t ws_size, hipStream_t stream) {
    const float* x = (const float*)d_in[0];
    const float* y = (const float*)d_in[1];
    const float* W = (const float*)d_in[2];
    float* out = (float*)d_out;

    char* ws = (char*)d_ws;
    int* cnt = (int*)ws;                                            // 16 B
    int* idx = (int*)(ws + 64);                                     // 512 KB
    unsigned short* Wt = (unsigned short*)(ws + 64 + NE * NS * 4);  // 512 KB
    int* bcnt = (int*)(ws + 64 + NE * NS * 4 + 16 * 16384 * 2);     // 2 KB

    prep_count<<<16 + 128, 256, 0, stream>>>(W, Wt, y, bcnt);
    prep_fill<<<128, 256, 0, stream>>>(y, bcnt, idx, cnt);
    // 4 experts x 512 super-tiles x 2 pairs (worst-case grid, early exit).
    gemm_main<<<4096, 256, 0, stream>>>(x, Wt, cnt, idx, out);
}

// Round 13
// 134.902 us; speedup vs baseline: 1.8623x; 1.8623x over previous
//
#include <hip/hip_runtime.h>

#define NS 32768
#define NE 4

typedef __attribute__((ext_vector_type(4))) float f32x4;
typedef __attribute__((ext_vector_type(8))) short bf16x8;

// fp32 -> bf16, round-to-nearest-even
__device__ __forceinline__ unsigned short f2bf(float f) {
    unsigned int u = __float_as_uint(f);
    u = (u + 0x7fffu + ((u >> 16) & 1u)) >> 16;
    return (unsigned short)u;
}

__device__ __forceinline__ int expert_of(const float4 yr) {
    int e = 0;
    if (yr.y > 0.5f) e = 1;
    else if (yr.z > 0.5f) e = 2;
    else if (yr.w > 0.5f) e = 3;
    return e;
}

// Prep A: blocks 0..15 transpose W -> Wt bf16; blocks 16..143 count experts
// per 256-sample chunk into bcnt[e][chunk] (block-exclusive, no atomics).
__global__ void prep_count(const float* __restrict__ W,
                           unsigned short* __restrict__ Wt,
                           const float* __restrict__ y,
                           int* __restrict__ bcnt) {
    const int b = blockIdx.x;
    if (b < 16) {
        const float* w = W + (size_t)b * 16384;         // [c][k]
        unsigned short* wt = Wt + (size_t)b * 16384;    // [k][c]
        for (int i = threadIdx.x; i < 16384; i += 256) {
            int c = i & 127, k = i >> 7;
            wt[k * 128 + c] = f2bf(w[c * 128 + k]);
        }
        return;
    }
    __shared__ int c[4][4];                             // [wave][expert]
    const int blk = b - 16;                             // 0..127
    int n = blk * 256 + threadIdx.x;
    int e = expert_of(((const float4*)y)[n]);
    const int lane = threadIdx.x & 63;
    const int wv = threadIdx.x >> 6;
#pragma unroll
    for (int ee = 0; ee < NE; ++ee) {
        unsigned long long m = __ballot(e == ee);
        if (lane == 0) c[wv][ee] = __popcll(m);
    }
    __syncthreads();
    if (threadIdx.x < 4)
        bcnt[threadIdx.x * 128 + blk] = c[0][threadIdx.x] + c[1][threadIdx.x] +
                                        c[2][threadIdx.x] + c[3][threadIdx.x];
}

// Prep B (merged scan+fill): each block computes its own expert offsets by
// wave-reducing bcnt directly (wave w = expert w), then writes idx sorted by
// n within each expert (deterministic). Block 0 also writes cnt totals.
__global__ void prep_fill(const float* __restrict__ y,
                          const int* __restrict__ bcnt, int* __restrict__ idx,
                          int* __restrict__ cnt) {
    __shared__ int sh_boff[4];
    __shared__ int wcnt[4][4];                // [wave][expert]
    const int blk = blockIdx.x;               // 0..127
    const int lane = threadIdx.x & 63;
    const int wv = threadIdx.x >> 6;          // 0..3 == expert for the scan
    {
        int c0 = bcnt[wv * 128 + lane];
        int c1 = bcnt[wv * 128 + 64 + lane];
        int part = ((lane < blk) ? c0 : 0) + ((lane + 64 < blk) ? c1 : 0);
        int tot = c0 + c1;
#pragma unroll
        for (int d = 1; d < 64; d <<= 1) {
            part += __shfl_xor(part, d);
            tot += __shfl_xor(tot, d);
        }
        if (lane == 0) {
            sh_boff[wv] = part;
            if (blk == 0) cnt[wv] = tot;
        }
    }
    int n = blk * 256 + threadIdx.x;
    int e = expert_of(((const float4*)y)[n]);
    int rank = 0;
#pragma unroll
    for (int ee = 0; ee < NE; ++ee) {
        unsigned long long m = __ballot(e == ee);
        if (lane == 0) wcnt[wv][ee] = __popcll(m);
        if (e == ee) rank = __popcll(m & ((1ull << lane) - 1ull));
    }
    __syncthreads();
#pragma unroll
    for (int w = 0; w < 4; ++w)
        if (w < wv) rank += wcnt[w][e];
    idx[e * NS + sh_boff[e] + rank] = n;
}

// LDS layout: [0, 32768)  weight panel bf16 [k=128][c=128], XOR-swizzled
//             [32768, 65536) per-wave x tiles bf16 [16 rows][c=128], swizzled
// Swizzle: byte ^= ((row & 7) << 4)  -> conflict-free ds_read_b128 fragments.
// 512-thread blocks: 8 waves share one weight panel; 64 KB LDS -> 2 blocks/CU
// -> 16 waves/CU.
template <int L, int M>
__device__ __forceinline__ void gemm_body(
    int e, int bi, int nb, unsigned char* lds, const float* __restrict__ x,
    const unsigned short* __restrict__ Wt, const int* __restrict__ cnt,
    const int* __restrict__ idx, float* __restrict__ out) {
    const int rows_total = cnt[e] * M;

    // Stage weight panel once per block; contiguous 8 KB per instruction.
    {
        const unsigned char* wp =
            (const unsigned char*)(Wt + (size_t)(e * 4 + L) * 16384);
        const int t = threadIdx.x;
#pragma unroll
        for (int q = 0; q < 4; ++q) {
            int o = q * 8192 + t * 16;
            uint4 v = *(const uint4*)(wp + o);
            int so = o ^ (((o >> 8) & 7) << 4);   // o>>8 = k row (256 B rows)
            *(uint4*)(lds + so) = v;
        }
    }
    __syncthreads();

    const int lane = threadIdx.x & 63;
    const int wv = threadIdx.x >> 6;  // 0..7
    const int li = lane & 15;
    const int half = lane >> 4;   // 0..3
    const int i5 = lane >> 5;     // 0..1
    const int c32 = lane & 31;
    const int* idxe = idx + e * NS;
    unsigned char* xl = lds + 32768 + wv * 4096;  // this wave's private x tile

    // One tile-iteration covers 128 rows (8 waves x 16 rows).
    for (int tile = bi; tile * 128 < rows_total; tile += nb) {
        const int gbase = tile * 128 + wv * 16;

        // Per-lane epilogue row (lane li owns gathered row gbase+li).
        int g = gbase + li;
        bool valid = g < rows_total;
        int gc = valid ? g : rows_total - 1;      // clamp for safe loads
        int pos = gc / M;                         // compile-time M -> magic
        int jj = gc - pos * M;
        int xrow = idxe[pos] * 16 + L * L + jj;

        // Stage 16 rows: instr q covers rows 2q,2q+1 fully contiguous.
        // Independent idx loads per q (all hit 1-2 L1-hot lines) ->
        // 8 parallel idx->x address chains, no bpermute.
        f32x4 bv[8];
#pragma unroll
        for (int q = 0; q < 8; ++q) {
            int gt = gbase + 2 * q + i5;
            int gtc = gt < rows_total ? gt : rows_total - 1;
            int p = gtc / M;
            int jq = gtc - p * M;
            int nr = idxe[p] * 16 + L * L + jq;
            bv[q] = *(const f32x4*)(x + (size_t)nr * 128 + c32 * 4);
        }
#pragma unroll
        for (int q = 0; q < 8; ++q) {
            int tr = 2 * q + i5;
            unsigned int p0 = (unsigned int)f2bf(bv[q].x) |
                              ((unsigned int)f2bf(bv[q].y) << 16);
            unsigned int p1 = (unsigned int)f2bf(bv[q].z) |
                              ((unsigned int)f2bf(bv[q].w) << 16);
            uint2 pk; pk.x = p0; pk.y = p1;
            int off = (c32 * 8) ^ ((tr & 7) << 4);
            *(uint2*)(xl + tr * 256 + off) = pk;
        }

        f32x4 acc[8];
#pragma unroll
        for (int t = 0; t < 8; ++t) acc[t] = (f32x4){0.f, 0.f, 0.f, 0.f};

#pragma unroll
        for (int kk = 0; kk < 4; ++kk) {
            int co = (kk * 64 + half * 16) ^ ((li & 7) << 4);
            bf16x8 bfrag = *(const bf16x8*)(xl + li * 256 + co);
#pragma unroll
            for (int t = 0; t < 8; ++t) {
                bf16x8 afrag = *(const bf16x8*)(lds + (t * 16 + li) * 256 + co);
                acc[t] = __builtin_amdgcn_mfma_f32_16x16x32_bf16(afrag, bfrag,
                                                                 acc[t], 0, 0, 0);
            }
        }

        if (valid) {
            float* orow = out + (size_t)xrow * 128;
            const float pw = 0.088388347648318447f;  // 1/sqrt(128)
#pragma unroll
            for (int t = 0; t < 8; ++t) {
                *(f32x4*)(orow + t * 16 + half * 4) = acc[t] * pw;
            }
        }
    }
}

// XCD-aware co-scheduling (T1): hardware dispatches block b to XCD b%8.
// Give XCD x, for EVERY (e,l), exactly the blocks covering fraction window
// [x/8, (x+1)/8) of that expert's sorted sample list:
//   l0 (16 blocks): bi = x*2  + s, s in [0,2)
//   l1 (48):        bi = x*6  + s, s in [0,6)
//   l2 (80):        bi = x*10 + s, s in [0,10)
//   l3 (112):       bi = x*14 + s, s in [0,14)
// Bijective; each 8 KB x/out sample-slab is then touched only by blocks on
// one XCD -> the four l-streams' partial-slab reads merge in that XCD's L2.
__global__ __launch_bounds__(512, 2) void gemm_main(
    const float* __restrict__ x, const unsigned short* __restrict__ Wt,
    const int* __restrict__ cnt, const int* __restrict__ idx,
    float* __restrict__ out) {
    __shared__ __align__(16) unsigned char lds[65536];
    const int b = blockIdx.x;
    const int xcd = b & 7;
    const int j = b >> 3;                 // within-XCD slot, 0..127
    const int e = j >> 5;                 // 32 slots per expert per XCD
    const int slot = j & 31;
    if (slot < 2)
        gemm_body<0, 1>(e, xcd * 2 + slot, 16, lds, x, Wt, cnt, idx, out);
    else if (slot < 8)
        gemm_body<1, 3>(e, xcd * 6 + (slot - 2), 48, lds, x, Wt, cnt, idx, out);
    else if (slot < 18)
        gemm_body<2, 5>(e, xcd * 10 + (slot - 8), 80, lds, x, Wt, cnt, idx, out);
    else
        gemm_body<3, 7>(e, xcd * 14 + (slot - 18), 112, lds, x, Wt, cnt, idx, out);
}

extern "C" void kernel_launch(void* const* d_in, const int* in_sizes, int n_in,
                              void* d_out, int out_size, void* d_ws,
                              size_t ws_size, hipStream_t stream) {
    const float* x = (const float*)d_in[0];
    const float* y = (const float*)d_in[1];
    const float* W = (const float*)d_in[2];
    float* out = (float*)d_out;

    char* ws = (char*)d_ws;
    int* cnt = (int*)ws;                                            // 16 B
    int* idx = (int*)(ws + 64);                                     // 512 KB
    unsigned short* Wt = (unsigned short*)(ws + 64 + NE * NS * 4);  // 512 KB
    int* bcnt = (int*)(ws + 64 + NE * NS * 4 + 16 * 16384 * 2);     // 2 KB

    prep_count<<<16 + 128, 256, 0, stream>>>(W, Wt, y, bcnt);
    prep_fill<<<128, 256, 0, stream>>>(y, bcnt, idx, cnt);
    gemm_main<<<1024, 512, 0, stream>>>(x, Wt, cnt, idx, out);
}